// Round 1
// baseline (200.588 us; speedup 1.0000x reference)
//
#include <hip/hip_runtime.h>

#define B_  2
#define S_  768
#define D_  768
#define H_  8
#define DH_ 96

typedef unsigned short ushort_t;
typedef __bf16 bf16x8 __attribute__((ext_vector_type(8)));
typedef float  f32x4  __attribute__((ext_vector_type(4)));

__device__ inline ushort_t f2bf(float f) {
    union { float f; unsigned int u; } v; v.f = f;
    unsigned int u = v.u;
    unsigned int r = u + 0x7fffu + ((u >> 16) & 1u);
    return (ushort_t)(r >> 16);
}
__device__ inline float bf2f(ushort_t u) {
    union { unsigned int i; float f; } c; c.i = ((unsigned int)u) << 16;
    return c.f;
}

// ---------------------------------------------------------------- convert
// X (1,179,648 f32) -> Xb bf16 ; Wq,Wk,Wv,Wo -> Wb bf16 [3072 x 768]
__global__ __launch_bounds__(256) void k_convert(
        const float* __restrict__ X, const float* __restrict__ Wq,
        const float* __restrict__ Wk, const float* __restrict__ Wv,
        const float* __restrict__ Wo,
        ushort_t* __restrict__ Xb, ushort_t* __restrict__ Wb) {
    const int NX4 = (B_ * S_ * D_) / 4;   // 294912
    const int NW4 = (D_ * D_) / 4;        // 147456
    int i = blockIdx.x * blockDim.x + threadIdx.x;   // vec4 index
    float4 v;
    ushort_t* dst;
    if (i < NX4) {
        v = ((const float4*)X)[i];
        dst = Xb + i * 4;
    } else {
        int wi = i - NX4;
        int sel = wi / NW4;
        int off = wi - sel * NW4;
        const float* src = (sel == 0) ? Wq : (sel == 1) ? Wk : (sel == 2) ? Wv : Wo;
        v = ((const float4*)src)[off];
        dst = Wb + wi * 4;
    }
    ushort4 o;
    o.x = f2bf(v.x); o.y = f2bf(v.y); o.z = f2bf(v.z); o.w = f2bf(v.w);
    *(ushort4*)dst = o;
}

// ---------------------------------------------------------------- GEMM core
// C = A * Bt^T ; A [M,K] bf16 row-major (lda), Bt [N,K] bf16 row-major (ldb).
// 64x64 block tile, 256 threads = 4 waves in 2x2, each wave 2x2 mfma 16x16x32.
// LDS row stride 48 elems (96B, 16B-aligned rows).
__device__ inline void gemm_bf16_64x64(
        const ushort_t* __restrict__ A, int lda,
        const ushort_t* __restrict__ Bt, int ldb, int maxBr,
        int K, int m0, int n0,
        ushort_t* As, ushort_t* Bs, f32x4 acc[2][2]) {
    const int tid  = threadIdx.x;
    const int lane = tid & 63, wave = tid >> 6;
    const int wm = (wave >> 1) * 32, wn = (wave & 1) * 32;
    const int lr = tid >> 2, lc = (tid & 3) * 8;
    const int fr = lane & 15, fk = (lane >> 4) * 8;
    int br = n0 + lr; if (br > maxBr) br = maxBr;
    const ushort_t* Arow = A + (size_t)(m0 + lr) * lda + lc;
    const ushort_t* Brow = Bt + (size_t)br * ldb + lc;
    for (int kt = 0; kt < K; kt += 32) {
        if (kt) __syncthreads();
        *(uint4*)&As[lr * 48 + lc] = *(const uint4*)(Arow + kt);
        *(uint4*)&Bs[lr * 48 + lc] = *(const uint4*)(Brow + kt);
        __syncthreads();
        bf16x8 a0 = *(const bf16x8*)&As[(wm      + fr) * 48 + fk];
        bf16x8 a1 = *(const bf16x8*)&As[(wm + 16 + fr) * 48 + fk];
        bf16x8 b0 = *(const bf16x8*)&Bs[(wn      + fr) * 48 + fk];
        bf16x8 b1 = *(const bf16x8*)&Bs[(wn + 16 + fr) * 48 + fk];
        acc[0][0] = __builtin_amdgcn_mfma_f32_16x16x32_bf16(a0, b0, acc[0][0], 0, 0, 0);
        acc[0][1] = __builtin_amdgcn_mfma_f32_16x16x32_bf16(a0, b1, acc[0][1], 0, 0, 0);
        acc[1][0] = __builtin_amdgcn_mfma_f32_16x16x32_bf16(a1, b0, acc[1][0], 0, 0, 0);
        acc[1][1] = __builtin_amdgcn_mfma_f32_16x16x32_bf16(a1, b1, acc[1][1], 0, 0, 0);
    }
}

// Variant with A in f32 (converted to bf16 while staging).
__device__ inline void gemm_f32a_64x64(
        const float* __restrict__ A, int lda,
        const ushort_t* __restrict__ Bt, int ldb, int maxBr,
        int K, int m0, int n0,
        ushort_t* As, ushort_t* Bs, f32x4 acc[2][2]) {
    const int tid  = threadIdx.x;
    const int lane = tid & 63, wave = tid >> 6;
    const int wm = (wave >> 1) * 32, wn = (wave & 1) * 32;
    const int lr = tid >> 2, lc = (tid & 3) * 8;
    const int fr = lane & 15, fk = (lane >> 4) * 8;
    int br = n0 + lr; if (br > maxBr) br = maxBr;
    const float*    Arow = A  + (size_t)(m0 + lr) * lda + lc;
    const ushort_t* Brow = Bt + (size_t)br * ldb + lc;
    for (int kt = 0; kt < K; kt += 32) {
        if (kt) __syncthreads();
        float4 x0 = *(const float4*)(Arow + kt);
        float4 x1 = *(const float4*)(Arow + kt + 4);
        ushort4 o0, o1;
        o0.x = f2bf(x0.x); o0.y = f2bf(x0.y); o0.z = f2bf(x0.z); o0.w = f2bf(x0.w);
        o1.x = f2bf(x1.x); o1.y = f2bf(x1.y); o1.z = f2bf(x1.z); o1.w = f2bf(x1.w);
        *(ushort4*)&As[lr * 48 + lc]     = o0;
        *(ushort4*)&As[lr * 48 + lc + 4] = o1;
        *(uint4*)&Bs[lr * 48 + lc] = *(const uint4*)(Brow + kt);
        __syncthreads();
        bf16x8 a0 = *(const bf16x8*)&As[(wm      + fr) * 48 + fk];
        bf16x8 a1 = *(const bf16x8*)&As[(wm + 16 + fr) * 48 + fk];
        bf16x8 b0 = *(const bf16x8*)&Bs[(wn      + fr) * 48 + fk];
        bf16x8 b1 = *(const bf16x8*)&Bs[(wn + 16 + fr) * 48 + fk];
        acc[0][0] = __builtin_amdgcn_mfma_f32_16x16x32_bf16(a0, b0, acc[0][0], 0, 0, 0);
        acc[0][1] = __builtin_amdgcn_mfma_f32_16x16x32_bf16(a0, b1, acc[0][1], 0, 0, 0);
        acc[1][0] = __builtin_amdgcn_mfma_f32_16x16x32_bf16(a1, b0, acc[1][0], 0, 0, 0);
        acc[1][1] = __builtin_amdgcn_mfma_f32_16x16x32_bf16(a1, b1, acc[1][1], 0, 0, 0);
    }
}

// ---------------------------------------------------------------- QKV GEMM
// Y = Xb @ Wb[0:2304]^T + bias ; writes Q,K as [BH, S, 96] bf16, V transposed
// as Vt [BH, 96, S] bf16.
__global__ __launch_bounds__(256) void k_qkv(
        const ushort_t* __restrict__ Xb, const ushort_t* __restrict__ Wb,
        const float* __restrict__ bq, const float* __restrict__ bk,
        const float* __restrict__ bv,
        ushort_t* __restrict__ Qb, ushort_t* __restrict__ Kb,
        ushort_t* __restrict__ Vtb) {
    __shared__ __align__(16) ushort_t As[64 * 48];
    __shared__ __align__(16) ushort_t Bs[64 * 48];
    f32x4 acc[2][2];
    #pragma unroll
    for (int i = 0; i < 2; i++)
        #pragma unroll
        for (int j = 0; j < 2; j++) acc[i][j] = (f32x4){0.f, 0.f, 0.f, 0.f};
    const int m0 = blockIdx.y * 64, n0 = blockIdx.x * 64;
    gemm_bf16_64x64(Xb, D_, Wb, D_, 3 * D_ - 1, D_, m0, n0, As, Bs, acc);
    const int lane = threadIdx.x & 63, wave = threadIdx.x >> 6;
    const int wm = (wave >> 1) * 32, wn = (wave & 1) * 32;
    #pragma unroll
    for (int ni = 0; ni < 2; ni++) {
        int gcol = n0 + wn + ni * 16 + (lane & 15);
        int g = gcol / D_, d768 = gcol - g * D_;
        int h = d768 / DH_, d = d768 - h * DH_;
        float bias = (g == 0 ? bq : (g == 1 ? bk : bv))[d768];
        #pragma unroll
        for (int mi = 0; mi < 2; mi++) {
            #pragma unroll
            for (int r = 0; r < 4; r++) {
                int grow = m0 + wm + mi * 16 + (lane >> 4) * 4 + r;
                int b = grow / S_, s = grow - b * S_;
                ushort_t ob = f2bf(acc[mi][ni][r] + bias);
                int bh = b * H_ + h;
                if (g == 0)      Qb[((size_t)bh * S_ + s) * DH_ + d] = ob;
                else if (g == 1) Kb[((size_t)bh * S_ + s) * DH_ + d] = ob;
                else             Vtb[((size_t)bh * DH_ + d) * S_ + s] = ob;
            }
        }
    }
}

// ---------------------------------------------------------------- qcoef
// per q-row (BH*S rows): c0=q.Wd, c1=q.Wa, c2=q.(bd+ba)
__global__ __launch_bounds__(256) void k_qcoef(
        const ushort_t* __restrict__ Qb,
        const float* __restrict__ Wd, const float* __restrict__ bd,
        const float* __restrict__ Wa, const float* __restrict__ ba,
        float* __restrict__ qcoef) {
    const int wave = threadIdx.x >> 6, lane = threadIdx.x & 63;
    const int row = blockIdx.x * 4 + wave;     // 0..12287
    const ushort_t* q = Qb + (size_t)row * DH_;
    float e0 = bf2f(q[lane]);
    float c0 = e0 * Wd[lane];
    float c1 = e0 * Wa[lane];
    float c2 = e0 * (bd[lane] + ba[lane]);
    if (lane < 32) {
        int d = 64 + lane;
        float e1 = bf2f(q[d]);
        c0 += e1 * Wd[d];
        c1 += e1 * Wa[d];
        c2 += e1 * (bd[d] + ba[d]);
    }
    #pragma unroll
    for (int o = 32; o > 0; o >>= 1) {
        c0 += __shfl_down(c0, o);
        c1 += __shfl_down(c1, o);
        c2 += __shfl_down(c2, o);
    }
    if (lane == 0) {
        qcoef[row * 3 + 0] = c0;
        qcoef[row * 3 + 1] = c1;
        qcoef[row * 3 + 2] = c2;
    }
}

// ---------------------------------------------------------------- scores
// raw scores -> probs buffer (f32): s = qk/sqrt(96) + dist*c0 + ang*c1 + c2 + maskb
__global__ __launch_bounds__(256) void k_scores(
        const ushort_t* __restrict__ Qb, const ushort_t* __restrict__ Kb,
        const float* __restrict__ qcoef,
        const float* __restrict__ distm, const float* __restrict__ angm,
        const float* __restrict__ mask, float* __restrict__ probs) {
    __shared__ __align__(16) ushort_t As[64 * 48];
    __shared__ __align__(16) ushort_t Bs[64 * 48];
    f32x4 acc[2][2];
    #pragma unroll
    for (int i = 0; i < 2; i++)
        #pragma unroll
        for (int j = 0; j < 2; j++) acc[i][j] = (f32x4){0.f, 0.f, 0.f, 0.f};
    const int bh = blockIdx.z, b = bh >> 3;
    const ushort_t* A  = Qb + (size_t)bh * S_ * DH_;
    const ushort_t* Bt = Kb + (size_t)bh * S_ * DH_;
    const int m0 = blockIdx.y * 64, n0 = blockIdx.x * 64;
    gemm_bf16_64x64(A, DH_, Bt, DH_, S_ - 1, DH_, m0, n0, As, Bs, acc);
    const int lane = threadIdx.x & 63, wave = threadIdx.x >> 6;
    const int wm = (wave >> 1) * 32, wn = (wave & 1) * 32;
    const float isq = 0.10206207261596577f;   // 1/sqrt(96)
    #pragma unroll
    for (int ni = 0; ni < 2; ni++) {
        int j = n0 + wn + ni * 16 + (lane & 15);
        float mb = (1.0f - mask[b * S_ + j]) * -10000.0f;
        #pragma unroll
        for (int mi = 0; mi < 2; mi++) {
            #pragma unroll
            for (int r = 0; r < 4; r++) {
                int i = m0 + wm + mi * 16 + (lane >> 4) * 4 + r;
                const float* qc = qcoef + ((size_t)bh * S_ + i) * 3;
                float dist = distm[((size_t)b * S_ + i) * S_ + j];
                float ang  = angm [((size_t)b * S_ + i) * S_ + j];
                float sres = acc[mi][ni][r] * isq + dist * qc[0] + ang * qc[1] + qc[2] + mb;
                probs[((size_t)bh * S_ + i) * S_ + j] = sres;
            }
        }
    }
}

// ---------------------------------------------------------------- softmax (in place, rows of 768)
__global__ __launch_bounds__(256) void k_softmax(float* __restrict__ probs) {
    float* p = probs + ((size_t)blockIdx.y * S_ + blockIdx.x) * S_;
    const int t = threadIdx.x;
    float v0 = p[t], v1 = p[t + 256], v2 = p[t + 512];
    __shared__ float rmax[4], rsum[4];
    float mx = fmaxf(v0, fmaxf(v1, v2));
    #pragma unroll
    for (int o = 32; o > 0; o >>= 1) mx = fmaxf(mx, __shfl_down(mx, o));
    if ((t & 63) == 0) rmax[t >> 6] = mx;
    __syncthreads();
    float m4 = fmaxf(fmaxf(rmax[0], rmax[1]), fmaxf(rmax[2], rmax[3]));
    float e0 = __expf(v0 - m4), e1 = __expf(v1 - m4), e2 = __expf(v2 - m4);
    float s = e0 + e1 + e2;
    #pragma unroll
    for (int o = 32; o > 0; o >>= 1) s += __shfl_down(s, o);
    if ((t & 63) == 0) rsum[t >> 6] = s;
    __syncthreads();
    float tot = rsum[0] + rsum[1] + rsum[2] + rsum[3];
    float inv = 1.0f / tot;
    p[t] = e0 * inv; p[t + 256] = e1 * inv; p[t + 512] = e2 * inv;
}

// ---------------------------------------------------------------- ctx = P @ V
// A = probs f32 [S,S] per bh ; Bt = Vt [96, S] bf16 ; writes ctx bf16 [B*S, 768]
__global__ __launch_bounds__(256) void k_ctx(
        const float* __restrict__ probs, const ushort_t* __restrict__ Vtb,
        ushort_t* __restrict__ Ctxb) {
    __shared__ __align__(16) ushort_t As[64 * 48];
    __shared__ __align__(16) ushort_t Bs[64 * 48];
    f32x4 acc[2][2];
    #pragma unroll
    for (int i = 0; i < 2; i++)
        #pragma unroll
        for (int j = 0; j < 2; j++) acc[i][j] = (f32x4){0.f, 0.f, 0.f, 0.f};
    const int bh = blockIdx.z, b = bh >> 3, h = bh & 7;
    const float*    A  = probs + (size_t)bh * S_ * S_;
    const ushort_t* Bt = Vtb + (size_t)bh * DH_ * S_;
    const int m0 = blockIdx.y * 64, n0 = blockIdx.x * 64;
    gemm_f32a_64x64(A, S_, Bt, S_, DH_ - 1, S_, m0, n0, As, Bs, acc);
    const int lane = threadIdx.x & 63, wave = threadIdx.x >> 6;
    const int wm = (wave >> 1) * 32, wn = (wave & 1) * 32;
    #pragma unroll
    for (int ni = 0; ni < 2; ni++) {
        int gcol = n0 + wn + ni * 16 + (lane & 15);
        if (gcol >= DH_) continue;
        #pragma unroll
        for (int mi = 0; mi < 2; mi++) {
            #pragma unroll
            for (int r = 0; r < 4; r++) {
                int i = m0 + wm + mi * 16 + (lane >> 4) * 4 + r;
                Ctxb[((size_t)(b * S_ + i)) * D_ + h * DH_ + gcol] = f2bf(acc[mi][ni][r]);
            }
        }
    }
}

// ---------------------------------------------------------------- out GEMM + bias + residual
__global__ __launch_bounds__(256) void k_out(
        const ushort_t* __restrict__ Ctxb, const ushort_t* __restrict__ Wob,
        const float* __restrict__ bo, const float* __restrict__ hidden,
        float* __restrict__ xbuf) {
    __shared__ __align__(16) ushort_t As[64 * 48];
    __shared__ __align__(16) ushort_t Bs[64 * 48];
    f32x4 acc[2][2];
    #pragma unroll
    for (int i = 0; i < 2; i++)
        #pragma unroll
        for (int j = 0; j < 2; j++) acc[i][j] = (f32x4){0.f, 0.f, 0.f, 0.f};
    const int m0 = blockIdx.y * 64, n0 = blockIdx.x * 64;
    gemm_bf16_64x64(Ctxb, D_, Wob, D_, D_ - 1, D_, m0, n0, As, Bs, acc);
    const int lane = threadIdx.x & 63, wave = threadIdx.x >> 6;
    const int wm = (wave >> 1) * 32, wn = (wave & 1) * 32;
    #pragma unroll
    for (int ni = 0; ni < 2; ni++) {
        int gcol = n0 + wn + ni * 16 + (lane & 15);
        float bias = bo[gcol];
        #pragma unroll
        for (int mi = 0; mi < 2; mi++) {
            #pragma unroll
            for (int r = 0; r < 4; r++) {
                int grow = m0 + wm + mi * 16 + (lane >> 4) * 4 + r;
                float val = acc[mi][ni][r] + bias + hidden[(size_t)grow * D_ + gcol];
                xbuf[(size_t)grow * D_ + gcol] = val;
            }
        }
    }
}

// ---------------------------------------------------------------- LayerNorm
__global__ __launch_bounds__(256) void k_ln(
        const float* __restrict__ xbuf, const float* __restrict__ g,
        const float* __restrict__ bb, float* __restrict__ out) {
    const float* x = xbuf + (size_t)blockIdx.x * D_;
    const int t = threadIdx.x;
    float a0 = x[t], a1 = x[t + 256], a2 = x[t + 512];
    float s = a0 + a1 + a2;
    float ss = a0 * a0 + a1 * a1 + a2 * a2;
    __shared__ float r1[4], r2[4];
    #pragma unroll
    for (int o = 32; o > 0; o >>= 1) { s += __shfl_down(s, o); ss += __shfl_down(ss, o); }
    if ((t & 63) == 0) { r1[t >> 6] = s; r2[t >> 6] = ss; }
    __syncthreads();
    float ts = r1[0] + r1[1] + r1[2] + r1[3];
    float tss = r2[0] + r2[1] + r2[2] + r2[3];
    float mu = ts * (1.0f / D_);
    float var = tss * (1.0f / D_) - mu * mu;
    float rstd = rsqrtf(var + 1e-5f);
    float* o = out + (size_t)blockIdx.x * D_;
    o[t]       = (a0 - mu) * rstd * g[t]       + bb[t];
    o[t + 256] = (a1 - mu) * rstd * g[t + 256] + bb[t + 256];
    o[t + 512] = (a2 - mu) * rstd * g[t + 512] + bb[t + 512];
}

// ---------------------------------------------------------------- launch
extern "C" void kernel_launch(void* const* d_in, const int* in_sizes, int n_in,
                              void* d_out, int out_size, void* d_ws, size_t ws_size,
                              hipStream_t stream) {
    const float* X     = (const float*)d_in[0];
    const float* distm = (const float*)d_in[1];
    const float* angm  = (const float*)d_in[2];
    const float* mask  = (const float*)d_in[3];
    const float* Wq    = (const float*)d_in[4];
    const float* bq    = (const float*)d_in[5];
    const float* Wk    = (const float*)d_in[6];
    const float* bk    = (const float*)d_in[7];
    const float* Wv    = (const float*)d_in[8];
    const float* bv    = (const float*)d_in[9];
    const float* Wd    = (const float*)d_in[10];
    const float* bd    = (const float*)d_in[11];
    const float* Wa    = (const float*)d_in[12];
    const float* ba    = (const float*)d_in[13];
    const float* Wo    = (const float*)d_in[14];
    const float* bo    = (const float*)d_in[15];
    const float* ln_g  = (const float*)d_in[16];
    const float* ln_b  = (const float*)d_in[17];

    float* outp  = (float*)d_out;                       // [B,S,D]
    float* probs = (float*)d_out + (size_t)B_ * S_ * D_; // [B,H,S,S]

    char* ws = (char*)d_ws;
    ushort_t* Xb    = (ushort_t*)(ws + 0);          // 2,359,296 B
    ushort_t* Wb    = (ushort_t*)(ws + 2359296);    // 4,718,592 B (Wq|Wk|Wv|Wo rows)
    ushort_t* Qb    = (ushort_t*)(ws + 7077888);    // 2,359,296 B
    ushort_t* Kb    = (ushort_t*)(ws + 9437184);    // 2,359,296 B
    ushort_t* Vtb   = (ushort_t*)(ws + 11796480);   // 2,359,296 B
    ushort_t* Ctxb  = (ushort_t*)(ws + 14155776);   // 2,359,296 B
    float*    qcoef = (float*)   (ws + 16515072);   //   147,456 B
    float*    xbuf  = (float*)   (ws + 16662528);   // 4,718,592 B  (end ~20.4 MB)

    k_convert<<<3456, 256, 0, stream>>>(X, Wq, Wk, Wv, Wo, Xb, Wb);
    k_qkv<<<dim3(36, 24), 256, 0, stream>>>(Xb, Wb, bq, bk, bv, Qb, Kb, Vtb);
    k_qcoef<<<3072, 256, 0, stream>>>(Qb, Wd, bd, Wa, ba, qcoef);
    k_scores<<<dim3(12, 12, 16), 256, 0, stream>>>(Qb, Kb, qcoef, distm, angm, mask, probs);
    k_softmax<<<dim3(768, 16), 256, 0, stream>>>(probs);
    k_ctx<<<dim3(2, 12, 16), 256, 0, stream>>>(probs, Vtb, Ctxb);
    k_out<<<dim3(12, 24), 256, 0, stream>>>(Ctxb, Wb + (size_t)2304 * 768, bo, X, xbuf);
    k_ln<<<1536, 256, 0, stream>>>(xbuf, ln_g, ln_b, outp);
}